// Round 1
// baseline (1582.961 us; speedup 1.0000x reference)
//
#include <hip/hip_runtime.h>
#include <math.h>

// Problem constants
//   B*S = 8192 tokens, K=8 selected neurons, N_BASIS=32, RANK=8
//   D_MODEL=256 (16x16), hidden 64 (8x8), D_HID=1024 (32x32)
// Workspace layout (floats): wr[8192][32] | h[8192][64] | g[8192][1024]  (~36.7 MB)

__device__ __forceinline__ float gelu_exact(float v) {
    return 0.5f * v * (1.0f + erff(v * 0.70710678118654752440f));
}

// ---------------- K1: routing -> wr[token][32] ----------------
__global__ __launch_bounds__(64) void k_route(
    const int* __restrict__ nidx, const float* __restrict__ nw,
    const float* __restrict__ recipes, float* __restrict__ wr_out)
{
    const int t = blockIdx.x * 64 + threadIdx.x;   // 8192 tokens
    float acc[32];
#pragma unroll
    for (int n = 0; n < 32; n++) acc[n] = 0.f;
#pragma unroll
    for (int k = 0; k < 8; k++) {
        const int   id = nidx[t * 8 + k];
        const float wk = nw[t * 8 + k];
        const float4* row = (const float4*)(recipes + id * 32);
        float v[32];
#pragma unroll
        for (int q = 0; q < 8; q++) {
            float4 f = row[q];
            v[q*4+0] = f.x; v[q*4+1] = f.y; v[q*4+2] = f.z; v[q*4+3] = f.w;
        }
        float m = v[0];
#pragma unroll
        for (int n = 1; n < 32; n++) m = fmaxf(m, v[n]);
        float s = 0.f;
#pragma unroll
        for (int n = 0; n < 32; n++) { float e = expf(v[n] - m); v[n] = e; s += e; }
        const float iv = wk / s;
#pragma unroll
        for (int n = 0; n < 32; n++) acc[n] += v[n] * iv;
    }
    float4* o = (float4*)(wr_out + t * 32);
#pragma unroll
    for (int q = 0; q < 8; q++)
        o[q] = make_float4(acc[q*4+0], acc[q*4+1], acc[q*4+2], acc[q*4+3]);
}

// ---------------- K2: stage A  x[256] -> h[64], 8 tokens/block ----------------
// cA1[i,r,k8] = sum_n wr[n]*A1[n,i,r,k]   (e = i*64 + r*8 + k)
// temp[j,r,k] = sum_i x[i*16+j]*cA1[i,r,k]
// cA2[r,j,l]  = sum_n wr[n]*A2[n,r,j,l]   (e = r*128 + j*8 + l)
// h[k*8+l]    = sum_{j,r} temp[j,r,k]*cA2[r,j,l]
__global__ __launch_bounds__(512) void k_stageA(
    const float* __restrict__ x, const float* __restrict__ wr,
    const float* __restrict__ A1, const float* __restrict__ A2,
    float* __restrict__ h_out)
{
    __shared__ float ca[8 * 1024];      // cores (cA1 then cA2), [t][1024]
    __shared__ float tl[8 * 1088];      // temp  [t][j(16)][68]
    const int tid = threadIdx.x;
    const int t0  = blockIdx.x * 8;

    // ---- build cA1: thread owns e2 = tid*2 for all 8 tokens (wr via uniform/scalar loads)
    {
        const int e2 = tid * 2;
        float2 c[8];
#pragma unroll
        for (int tt = 0; tt < 8; tt++) c[tt] = make_float2(0.f, 0.f);
#pragma unroll 4
        for (int n = 0; n < 32; n++) {
            const float2 a = *(const float2*)(A1 + n * 1024 + e2);
#pragma unroll
            for (int tt = 0; tt < 8; tt++) {
                const float s = wr[(t0 + tt) * 32 + n];   // uniform -> s_load
                c[tt].x += s * a.x; c[tt].y += s * a.y;
            }
        }
#pragma unroll
        for (int tt = 0; tt < 8; tt++) *(float2*)(ca + tt * 1024 + e2) = c[tt];
    }
    __syncthreads();

    // ---- temp build: thread (t = tid>>6, j = (tid&63)>>2, eh = tid&3) ----
    {
        const int t = tid >> 6, g = tid & 63, j = g >> 2, eh = g & 3;
        float xr[16];
#pragma unroll
        for (int i = 0; i < 16; i++) xr[i] = x[(t0 + t) * 256 + i * 16 + j];
        float tr[16];
#pragma unroll
        for (int q = 0; q < 16; q++) tr[q] = 0.f;
#pragma unroll
        for (int i = 0; i < 16; i++) {
            const float xv = xr[i];
#pragma unroll
            for (int q = 0; q < 4; q++) {
                const float4 cv = *(const float4*)(ca + t * 1024 + i * 64 + eh * 16 + q * 4);
                tr[q*4+0] += xv * cv.x; tr[q*4+1] += xv * cv.y;
                tr[q*4+2] += xv * cv.z; tr[q*4+3] += xv * cv.w;
            }
        }
#pragma unroll
        for (int q = 0; q < 4; q++)
            *(float4*)(tl + t * 1088 + j * 68 + eh * 16 + q * 4) =
                make_float4(tr[q*4+0], tr[q*4+1], tr[q*4+2], tr[q*4+3]);
    }
    __syncthreads();

    // ---- build cA2 into ca (overwrite) ----
    {
        const int e2 = tid * 2;
        float2 c[8];
#pragma unroll
        for (int tt = 0; tt < 8; tt++) c[tt] = make_float2(0.f, 0.f);
#pragma unroll 4
        for (int n = 0; n < 32; n++) {
            const float2 a = *(const float2*)(A2 + n * 1024 + e2);
#pragma unroll
            for (int tt = 0; tt < 8; tt++) {
                const float s = wr[(t0 + tt) * 32 + n];
                c[tt].x += s * a.x; c[tt].y += s * a.y;
            }
        }
#pragma unroll
        for (int tt = 0; tt < 8; tt++) *(float2*)(ca + tt * 1024 + e2) = c[tt];
    }
    __syncthreads();

    // ---- h: thread (t, k = (tid&63)>>3, l = tid&7) ----
    {
        const int t = tid >> 6, g = tid & 63, k = g >> 3, l = g & 7;
        float acc = 0.f;
#pragma unroll
        for (int j = 0; j < 16; j++) {
#pragma unroll
            for (int r = 0; r < 8; r++) {
                acc += tl[t * 1088 + j * 68 + r * 8 + k] *
                       ca[t * 1024 + r * 128 + j * 8 + l];
            }
        }
        h_out[(t0 + t) * 64 + g] = acc;
    }
}

// ---------------- K3: stage B  h[64] -> g[1024]=gelu(out), 8 tokens/block ----------------
// cB1[i,r,k32] (e = i*256 + r*32 + k) ; temp2[j,r,k] = sum_i h[i*8+j]*cB1[i,r,k]
// cB2[r,j,l32] (e = r*256 + j*32 + l) ; out[k,l] = sum_{j,r} temp2[j,r,k]*cB2[r,j,l]
__global__ __launch_bounds__(512) void k_stageB(
    const float* __restrict__ hin, const float* __restrict__ wr,
    const float* __restrict__ B1, const float* __restrict__ B2,
    float* __restrict__ g_out)
{
    __shared__ float t2l[8 * 2340];   // temp2 [t][j(8) stride 292][r(8) stride 36][k32]
    __shared__ float r2 [8 * 2340];   // cb1 (flat [t][2048]) then cB2 [t][r stride 292][j stride 36][l32]
    __shared__ float hs [8 * 64];
    const int tid = threadIdx.x;
    const int t0  = blockIdx.x * 8;

    hs[tid] = hin[t0 * 64 + tid];     // 512 threads, 512 floats
    __syncthreads();

    // ---- build cB1 into r2 (flat): thread owns q = tid*4, all 8 tokens ----
    {
        const int q = tid * 4;
        float4 c[8];
#pragma unroll
        for (int tt = 0; tt < 8; tt++) c[tt] = make_float4(0.f, 0.f, 0.f, 0.f);
#pragma unroll 4
        for (int n = 0; n < 32; n++) {
            const float4 a = *(const float4*)(B1 + n * 2048 + q);
#pragma unroll
            for (int tt = 0; tt < 8; tt++) {
                const float s = wr[(t0 + tt) * 32 + n];
                c[tt].x += s * a.x; c[tt].y += s * a.y;
                c[tt].z += s * a.z; c[tt].w += s * a.w;
            }
        }
#pragma unroll
        for (int tt = 0; tt < 8; tt++) *(float4*)(r2 + tt * 2340 + q) = c[tt];
    }
    __syncthreads();

    // ---- temp2 build: thread (t = tid>>6, j = tid&7, kq = (tid&63)>>3) ----
    {
        const int t = tid >> 6, g = tid & 63, j = g & 7, kq = g >> 3;
        float4 tr[8];
#pragma unroll
        for (int r = 0; r < 8; r++) tr[r] = make_float4(0.f, 0.f, 0.f, 0.f);
#pragma unroll
        for (int i = 0; i < 8; i++) {
            const float hv = hs[t * 64 + i * 8 + j];
#pragma unroll
            for (int r = 0; r < 8; r++) {
                const float4 cv = *(const float4*)(r2 + t * 2340 + i * 256 + r * 32 + kq * 4);
                tr[r].x += hv * cv.x; tr[r].y += hv * cv.y;
                tr[r].z += hv * cv.z; tr[r].w += hv * cv.w;
            }
        }
#pragma unroll
        for (int r = 0; r < 8; r++)
            *(float4*)(t2l + t * 2340 + j * 292 + r * 36 + kq * 4) = tr[r];
    }
    __syncthreads();

    // ---- build cB2 into r2 (overwrite cb1): padded layout ----
    {
        const int q  = tid * 4;
        const int rr = q >> 8, jj = (q >> 5) & 7, ll = q & 31;
        float4 c[8];
#pragma unroll
        for (int tt = 0; tt < 8; tt++) c[tt] = make_float4(0.f, 0.f, 0.f, 0.f);
#pragma unroll 4
        for (int n = 0; n < 32; n++) {
            const float4 a = *(const float4*)(B2 + n * 2048 + q);
#pragma unroll
            for (int tt = 0; tt < 8; tt++) {
                const float s = wr[(t0 + tt) * 32 + n];
                c[tt].x += s * a.x; c[tt].y += s * a.y;
                c[tt].z += s * a.z; c[tt].w += s * a.w;
            }
        }
#pragma unroll
        for (int tt = 0; tt < 8; tt++)
            *(float4*)(r2 + tt * 2340 + rr * 292 + jj * 36 + ll) = c[tt];
    }
    __syncthreads();

    // ---- out: thread (t, k0 = (tid&7)*4, l0 = ((tid&63)>>3)*4), 4x4 quad ----
    {
        const int t = tid >> 6, g = tid & 63, k0 = (g & 7) * 4, l0 = (g >> 3) * 4;
        float o[4][4];   // o[li][a] : a indexes k, li indexes l
#pragma unroll
        for (int li = 0; li < 4; li++)
#pragma unroll
            for (int a = 0; a < 4; a++) o[li][a] = 0.f;
#pragma unroll
        for (int j = 0; j < 8; j++) {
#pragma unroll
            for (int r = 0; r < 8; r++) {
                const float4 tv4 = *(const float4*)(t2l + t * 2340 + j * 292 + r * 36 + k0);
                const float4 cv4 = *(const float4*)(r2  + t * 2340 + r * 292 + j * 36 + l0);
                const float tv[4] = {tv4.x, tv4.y, tv4.z, tv4.w};
                const float cv[4] = {cv4.x, cv4.y, cv4.z, cv4.w};
#pragma unroll
                for (int li = 0; li < 4; li++)
#pragma unroll
                    for (int a = 0; a < 4; a++)
                        o[li][a] += tv[a] * cv[li];
            }
        }
        const int tok = t0 + t;
#pragma unroll
        for (int a = 0; a < 4; a++) {
            float4 vg;
            vg.x = gelu_exact(o[0][a]); vg.y = gelu_exact(o[1][a]);
            vg.z = gelu_exact(o[2][a]); vg.w = gelu_exact(o[3][a]);
            *(float4*)(g_out + tok * 1024 + (k0 + a) * 32 + l0) = vg;
        }
    }
}

// ---------------- K4: down-proj  y = g[8192x1024] @ W[1024x256] + b ----------------
// tile M64 x N128, block 256 (thread m4 x n(4+4)), grid 128*2
__global__ __launch_bounds__(256) void k_down(
    const float* __restrict__ g, const float* __restrict__ W,
    const float* __restrict__ bias, float* __restrict__ y)
{
    __shared__ float gl[64 * 21];    // [m][kk16] pad 21
    __shared__ float wl[16 * 132];   // [kk][n128] pad 132
    const int tid = threadIdx.x;
    const int m0 = (blockIdx.x >> 1) * 64;
    const int n0 = (blockIdx.x & 1) * 128;
    const int mi = tid >> 4, ni = tid & 15;

    float acc[4][8];
#pragma unroll
    for (int a = 0; a < 4; a++)
#pragma unroll
        for (int q = 0; q < 8; q++) acc[a][q] = 0.f;

    for (int kc = 0; kc < 1024; kc += 16) {
        __syncthreads();
        {   // stage g tile: thread stores 4 scalars (pad-21 rows)
            const int idx = tid * 4, m = idx >> 4, kk = idx & 15;
            const float4 v = *(const float4*)(g + (m0 + m) * 1024 + kc + kk);
            gl[m * 21 + kk + 0] = v.x; gl[m * 21 + kk + 1] = v.y;
            gl[m * 21 + kk + 2] = v.z; gl[m * 21 + kk + 3] = v.w;
        }
        {   // stage W tile: thread stores 8 floats
            const int idx = tid * 8, row = idx >> 7, col = idx & 127;
            const float4 v0 = *(const float4*)(W + (kc + row) * 256 + n0 + col);
            const float4 v1 = *(const float4*)(W + (kc + row) * 256 + n0 + col + 4);
            *(float4*)(wl + row * 132 + col)     = v0;
            *(float4*)(wl + row * 132 + col + 4) = v1;
        }
        __syncthreads();
#pragma unroll
        for (int kk = 0; kk < 16; kk++) {
            float gv[4];
#pragma unroll
            for (int a = 0; a < 4; a++) gv[a] = gl[(mi * 4 + a) * 21 + kk];
            const float4 w0 = *(const float4*)(wl + kk * 132 + ni * 4);
            const float4 w1 = *(const float4*)(wl + kk * 132 + 64 + ni * 4);
#pragma unroll
            for (int a = 0; a < 4; a++) {
                acc[a][0] += gv[a] * w0.x; acc[a][1] += gv[a] * w0.y;
                acc[a][2] += gv[a] * w0.z; acc[a][3] += gv[a] * w0.w;
                acc[a][4] += gv[a] * w1.x; acc[a][5] += gv[a] * w1.y;
                acc[a][6] += gv[a] * w1.z; acc[a][7] += gv[a] * w1.w;
            }
        }
    }
    const float4 b0 = *(const float4*)(bias + n0 + ni * 4);
    const float4 b1 = *(const float4*)(bias + n0 + 64 + ni * 4);
#pragma unroll
    for (int a = 0; a < 4; a++) {
        const int row = m0 + mi * 4 + a;
        float4 o0 = make_float4(acc[a][0] + b0.x, acc[a][1] + b0.y,
                                acc[a][2] + b0.z, acc[a][3] + b0.w);
        float4 o1 = make_float4(acc[a][4] + b1.x, acc[a][5] + b1.y,
                                acc[a][6] + b1.z, acc[a][7] + b1.w);
        *(float4*)(y + row * 256 + n0 + ni * 4)      = o0;
        *(float4*)(y + row * 256 + n0 + 64 + ni * 4) = o1;
    }
}

extern "C" void kernel_launch(void* const* d_in, const int* in_sizes, int n_in,
                              void* d_out, int out_size, void* d_ws, size_t ws_size,
                              hipStream_t stream)
{
    const float* x    = (const float*)d_in[0];
    const int*   nidx = (const int*)  d_in[1];
    const float* nw   = (const float*)d_in[2];
    const float* rec  = (const float*)d_in[3];
    const float* A1   = (const float*)d_in[4];
    const float* A2   = (const float*)d_in[5];
    const float* B1   = (const float*)d_in[6];
    const float* B2   = (const float*)d_in[7];
    const float* Wd   = (const float*)d_in[8];
    const float* bd   = (const float*)d_in[9];
    float* y  = (float*)d_out;

    float* wr = (float*)d_ws;                 // 8192*32
    float* h  = wr + 8192 * 32;               // 8192*64
    float* g  = h  + 8192 * 64;               // 8192*1024   (total ~36.7 MB of ws)

    k_route <<<128,  64, 0, stream>>>(nidx, nw, rec, wr);
    k_stageA<<<1024, 512, 0, stream>>>(x, wr, A1, A2, h);
    k_stageB<<<1024, 512, 0, stream>>>(h, wr, B1, B2, g);
    k_down  <<<256,  256, 0, stream>>>(g, Wd, bd, y);
}

// Round 2
// 271.592 us; speedup vs baseline: 5.8284x; 5.8284x over previous
//
#include <hip/hip_runtime.h>
#include <math.h>

// Problem constants
//   B*S = 8192 tokens, K=8 selected neurons, N_BASIS=32, RANK=8
//   D_MODEL=256 (16x16), hidden 64 (8x8), D_HID=1024 (32x32)
// Workspace layout (floats): wr[8192][32] | h[8192][64] | g[8192][1024]  (~36.7 MB)

__device__ __forceinline__ float gelu_exact(float v) {
    return 0.5f * v * (1.0f + erff(v * 0.70710678118654752440f));
}

// ---------------- K1: routing -> wr[token][32] ----------------
__global__ __launch_bounds__(64) void k_route(
    const int* __restrict__ nidx, const float* __restrict__ nw,
    const float* __restrict__ recipes, float* __restrict__ wr_out)
{
    const int t = blockIdx.x * 64 + threadIdx.x;   // 8192 tokens
    float acc[32];
#pragma unroll
    for (int n = 0; n < 32; n++) acc[n] = 0.f;
#pragma unroll
    for (int k = 0; k < 8; k++) {
        const int   id = nidx[t * 8 + k];
        const float wk = nw[t * 8 + k];
        const float4* row = (const float4*)(recipes + id * 32);
        float v[32];
#pragma unroll
        for (int q = 0; q < 8; q++) {
            float4 f = row[q];
            v[q*4+0] = f.x; v[q*4+1] = f.y; v[q*4+2] = f.z; v[q*4+3] = f.w;
        }
        float m = v[0];
#pragma unroll
        for (int n = 1; n < 32; n++) m = fmaxf(m, v[n]);
        float s = 0.f;
#pragma unroll
        for (int n = 0; n < 32; n++) { float e = expf(v[n] - m); v[n] = e; s += e; }
        const float iv = wk / s;
#pragma unroll
        for (int n = 0; n < 32; n++) acc[n] += v[n] * iv;
    }
    float4* o = (float4*)(wr_out + t * 32);
#pragma unroll
    for (int q = 0; q < 8; q++)
        o[q] = make_float4(acc[q*4+0], acc[q*4+1], acc[q*4+2], acc[q*4+3]);
}

// ---------------- K2: stage A  x[256] -> h[64], 8 tokens/block ----------------
// cA1[i,r,k8] = sum_n wr[n]*A1[n,i,r,k]   (e = i*64 + r*8 + k)
// temp[j,r,k] = sum_i x[i*16+j]*cA1[i,r,k]
// cA2[r,j,l]  = sum_n wr[n]*A2[n,r,j,l]   (e = r*128 + j*8 + l)
// h[k*8+l]    = sum_{j,r} temp[j,r,k]*cA2[r,j,l]
__global__ __launch_bounds__(512) void k_stageA(
    const float* __restrict__ x, const float* __restrict__ wr,
    const float* __restrict__ A1, const float* __restrict__ A2,
    float* __restrict__ h_out)
{
    __shared__ float ca[8 * 1024];      // cores (cA1 then cA2), [t][1024]
    __shared__ float tl[8 * 1088];      // temp  [t][j(16)][68]
    const int tid = threadIdx.x;
    const int t0  = blockIdx.x * 8;

    // ---- build cA1: thread owns e2 = tid*2 for all 8 tokens (wr via uniform/scalar loads)
    {
        const int e2 = tid * 2;
        float2 c[8];
#pragma unroll
        for (int tt = 0; tt < 8; tt++) c[tt] = make_float2(0.f, 0.f);
#pragma unroll 4
        for (int n = 0; n < 32; n++) {
            const float2 a = *(const float2*)(A1 + n * 1024 + e2);
#pragma unroll
            for (int tt = 0; tt < 8; tt++) {
                const float s = wr[(t0 + tt) * 32 + n];   // uniform -> s_load
                c[tt].x += s * a.x; c[tt].y += s * a.y;
            }
        }
#pragma unroll
        for (int tt = 0; tt < 8; tt++) *(float2*)(ca + tt * 1024 + e2) = c[tt];
    }
    __syncthreads();

    // ---- temp build: thread (t = tid>>6, j = (tid&63)>>2, eh = tid&3) ----
    {
        const int t = tid >> 6, g = tid & 63, j = g >> 2, eh = g & 3;
        float xr[16];
#pragma unroll
        for (int i = 0; i < 16; i++) xr[i] = x[(t0 + t) * 256 + i * 16 + j];
        float tr[16];
#pragma unroll
        for (int q = 0; q < 16; q++) tr[q] = 0.f;
#pragma unroll
        for (int i = 0; i < 16; i++) {
            const float xv = xr[i];
#pragma unroll
            for (int q = 0; q < 4; q++) {
                const float4 cv = *(const float4*)(ca + t * 1024 + i * 64 + eh * 16 + q * 4);
                tr[q*4+0] += xv * cv.x; tr[q*4+1] += xv * cv.y;
                tr[q*4+2] += xv * cv.z; tr[q*4+3] += xv * cv.w;
            }
        }
#pragma unroll
        for (int q = 0; q < 4; q++)
            *(float4*)(tl + t * 1088 + j * 68 + eh * 16 + q * 4) =
                make_float4(tr[q*4+0], tr[q*4+1], tr[q*4+2], tr[q*4+3]);
    }
    __syncthreads();

    // ---- build cA2 into ca (overwrite) ----
    {
        const int e2 = tid * 2;
        float2 c[8];
#pragma unroll
        for (int tt = 0; tt < 8; tt++) c[tt] = make_float2(0.f, 0.f);
#pragma unroll 4
        for (int n = 0; n < 32; n++) {
            const float2 a = *(const float2*)(A2 + n * 1024 + e2);
#pragma unroll
            for (int tt = 0; tt < 8; tt++) {
                const float s = wr[(t0 + tt) * 32 + n];
                c[tt].x += s * a.x; c[tt].y += s * a.y;
            }
        }
#pragma unroll
        for (int tt = 0; tt < 8; tt++) *(float2*)(ca + tt * 1024 + e2) = c[tt];
    }
    __syncthreads();

    // ---- h: thread (t, k = (tid&63)>>3, l = tid&7) ----
    {
        const int t = tid >> 6, g = tid & 63, k = g >> 3, l = g & 7;
        float acc = 0.f;
#pragma unroll
        for (int j = 0; j < 16; j++) {
#pragma unroll
            for (int r = 0; r < 8; r++) {
                acc += tl[t * 1088 + j * 68 + r * 8 + k] *
                       ca[t * 1024 + r * 128 + j * 8 + l];
            }
        }
        h_out[(t0 + t) * 64 + g] = acc;
    }
}

// ---------------- K3: stage B  h[64] -> g[1024]=gelu(out), 8 tokens/block ----------------
// Rank-sliced: for r in 0..7:
//   cB1_r[t][i][k] = sum_n wr[t][n]*B1[n,i,r,k]     (i=8, k=32)
//   cB2_r[t][j][l] = sum_n wr[t][n]*B2[n,r,j,l]     (j=8, l=32)
//   t2_r [t][j][k] = sum_i hs[t][i*8+j]*cB1_r[t][i][k]
//   o[k][l]       += sum_j t2_r[t][j][k]*cB2_r[t][j][l]
// LDS ~28 KB, per-thread state <= ~50 VGPR (no spillable arrays).
__global__ __launch_bounds__(512) void k_stageB(
    const float* __restrict__ hin, const float* __restrict__ wr,
    const float* __restrict__ B1, const float* __restrict__ B2,
    float* __restrict__ g_out)
{
    __shared__ float wrs[8 * 33];     // [t][n] pad 33
    __shared__ float hs [8 * 64];     // [t][64]
    __shared__ float cb1[8 * 264];    // [t][i*32+k] pad 264
    __shared__ float cb2[8 * 264];    // [t][j*32+l] pad 264
    __shared__ float t2 [8 * 264];    // [t][j*32+k] pad 264
    const int tid = threadIdx.x;
    const int t0  = blockIdx.x * 8;

    if (tid < 256) wrs[(tid >> 5) * 33 + (tid & 31)] = wr[t0 * 32 + tid];
    hs[tid] = hin[t0 * 64 + tid];

    // P1 mapping: lane-fast token -> B loads broadcast across 8 lanes
    const int tB = tid & 7, pos = tid >> 3, iB = pos >> 3, c4 = pos & 7;
    // P2 mapping
    const int tP2 = tid >> 6, g2 = tid & 63, j2 = g2 >> 3, k42 = g2 & 7;
    // P3 mapping (output 4x4 tile per thread)
    const int tP3 = tid >> 6, g3 = tid & 63, k0 = (g3 & 7) * 4, l0 = (g3 >> 3) * 4;

    float o[4][4];   // o[a over k][li over l]
#pragma unroll
    for (int a = 0; a < 4; a++)
#pragma unroll
        for (int li = 0; li < 4; li++) o[a][li] = 0.f;

    const float* B1base = B1 + iB * 256 + c4 * 4;   // + r*32 + n*2048
    const float* B2base = B2 + iB * 32  + c4 * 4;   // + r*256 + n*2048 (iB plays j)

    __syncthreads();

    for (int r = 0; r < 8; r++) {
        // ---- P1: build cb1_r and cb2_r ----
        {
            float4 a1 = make_float4(0.f, 0.f, 0.f, 0.f);
            float4 a2 = make_float4(0.f, 0.f, 0.f, 0.f);
            const float* p1 = B1base + r * 32;
            const float* p2 = B2base + r * 256;
#pragma unroll 4
            for (int n = 0; n < 32; n++) {
                const float4 b1 = *(const float4*)(p1 + n * 2048);
                const float4 b2 = *(const float4*)(p2 + n * 2048);
                const float  s  = wrs[tB * 33 + n];
                a1.x += s * b1.x; a1.y += s * b1.y; a1.z += s * b1.z; a1.w += s * b1.w;
                a2.x += s * b2.x; a2.y += s * b2.y; a2.z += s * b2.z; a2.w += s * b2.w;
            }
            *(float4*)(cb1 + tB * 264 + iB * 32 + c4 * 4) = a1;
            *(float4*)(cb2 + tB * 264 + iB * 32 + c4 * 4) = a2;
        }
        __syncthreads();

        // ---- P2: t2_r[t][j][k] = sum_i hs[t][i*8+j] * cb1_r[t][i][k] ----
        {
            float4 acc = make_float4(0.f, 0.f, 0.f, 0.f);
#pragma unroll
            for (int i = 0; i < 8; i++) {
                const float  hv = hs[tP2 * 64 + i * 8 + j2];
                const float4 cv = *(const float4*)(cb1 + tP2 * 264 + i * 32 + k42 * 4);
                acc.x += hv * cv.x; acc.y += hv * cv.y;
                acc.z += hv * cv.z; acc.w += hv * cv.w;
            }
            *(float4*)(t2 + tP2 * 264 + j2 * 32 + k42 * 4) = acc;
        }
        __syncthreads();

        // ---- P3: o[a][li] += sum_j t2[t][j][k0+a] * cb2[t][j][l0+li] ----
        {
#pragma unroll
            for (int j = 0; j < 8; j++) {
                const float4 tv4 = *(const float4*)(t2  + tP3 * 264 + j * 32 + k0);
                const float4 cv4 = *(const float4*)(cb2 + tP3 * 264 + j * 32 + l0);
                const float tv[4] = {tv4.x, tv4.y, tv4.z, tv4.w};
                const float cv[4] = {cv4.x, cv4.y, cv4.z, cv4.w};
#pragma unroll
                for (int a = 0; a < 4; a++)
#pragma unroll
                    for (int li = 0; li < 4; li++)
                        o[a][li] += tv[a] * cv[li];
            }
        }
        __syncthreads();   // before overwriting cb1/cb2/t2 in next r-slice
    }

    // ---- gelu + store: thread writes rows k0..k0+3, cols l0..l0+3 of its token ----
    const int tok = t0 + tP3;
#pragma unroll
    for (int a = 0; a < 4; a++) {
        float4 vg;
        vg.x = gelu_exact(o[a][0]); vg.y = gelu_exact(o[a][1]);
        vg.z = gelu_exact(o[a][2]); vg.w = gelu_exact(o[a][3]);
        *(float4*)(g_out + tok * 1024 + (k0 + a) * 32 + l0) = vg;
    }
}

// ---------------- K4: down-proj  y = g[8192x1024] @ W[1024x256] + b ----------------
// tile M64 x N128, block 256 (thread m4 x n(4+4)), grid 128*2
__global__ __launch_bounds__(256) void k_down(
    const float* __restrict__ g, const float* __restrict__ W,
    const float* __restrict__ bias, float* __restrict__ y)
{
    __shared__ float gl[64 * 21];    // [m][kk16] pad 21
    __shared__ float wl[16 * 132];   // [kk][n128] pad 132
    const int tid = threadIdx.x;
    const int m0 = (blockIdx.x >> 1) * 64;
    const int n0 = (blockIdx.x & 1) * 128;
    const int mi = tid >> 4, ni = tid & 15;

    float acc[4][8];
#pragma unroll
    for (int a = 0; a < 4; a++)
#pragma unroll
        for (int q = 0; q < 8; q++) acc[a][q] = 0.f;

    for (int kc = 0; kc < 1024; kc += 16) {
        __syncthreads();
        {   // stage g tile: thread stores 4 scalars (pad-21 rows)
            const int idx = tid * 4, m = idx >> 4, kk = idx & 15;
            const float4 v = *(const float4*)(g + (m0 + m) * 1024 + kc + kk);
            gl[m * 21 + kk + 0] = v.x; gl[m * 21 + kk + 1] = v.y;
            gl[m * 21 + kk + 2] = v.z; gl[m * 21 + kk + 3] = v.w;
        }
        {   // stage W tile: thread stores 8 floats
            const int idx = tid * 8, row = idx >> 7, col = idx & 127;
            const float4 v0 = *(const float4*)(W + (kc + row) * 256 + n0 + col);
            const float4 v1 = *(const float4*)(W + (kc + row) * 256 + n0 + col + 4);
            *(float4*)(wl + row * 132 + col)     = v0;
            *(float4*)(wl + row * 132 + col + 4) = v1;
        }
        __syncthreads();
#pragma unroll
        for (int kk = 0; kk < 16; kk++) {
            float gv[4];
#pragma unroll
            for (int a = 0; a < 4; a++) gv[a] = gl[(mi * 4 + a) * 21 + kk];
            const float4 w0 = *(const float4*)(wl + kk * 132 + ni * 4);
            const float4 w1 = *(const float4*)(wl + kk * 132 + 64 + ni * 4);
#pragma unroll
            for (int a = 0; a < 4; a++) {
                acc[a][0] += gv[a] * w0.x; acc[a][1] += gv[a] * w0.y;
                acc[a][2] += gv[a] * w0.z; acc[a][3] += gv[a] * w0.w;
                acc[a][4] += gv[a] * w1.x; acc[a][5] += gv[a] * w1.y;
                acc[a][6] += gv[a] * w1.z; acc[a][7] += gv[a] * w1.w;
            }
        }
    }
    const float4 b0 = *(const float4*)(bias + n0 + ni * 4);
    const float4 b1 = *(const float4*)(bias + n0 + 64 + ni * 4);
#pragma unroll
    for (int a = 0; a < 4; a++) {
        const int row = m0 + mi * 4 + a;
        float4 o0 = make_float4(acc[a][0] + b0.x, acc[a][1] + b0.y,
                                acc[a][2] + b0.z, acc[a][3] + b0.w);
        float4 o1 = make_float4(acc[a][4] + b1.x, acc[a][5] + b1.y,
                                acc[a][6] + b1.z, acc[a][7] + b1.w);
        *(float4*)(y + row * 256 + n0 + ni * 4)      = o0;
        *(float4*)(y + row * 256 + n0 + 64 + ni * 4) = o1;
    }
}

extern "C" void kernel_launch(void* const* d_in, const int* in_sizes, int n_in,
                              void* d_out, int out_size, void* d_ws, size_t ws_size,
                              hipStream_t stream)
{
    const float* x    = (const float*)d_in[0];
    const int*   nidx = (const int*)  d_in[1];
    const float* nw   = (const float*)d_in[2];
    const float* rec  = (const float*)d_in[3];
    const float* A1   = (const float*)d_in[4];
    const float* A2   = (const float*)d_in[5];
    const float* B1   = (const float*)d_in[6];
    const float* B2   = (const float*)d_in[7];
    const float* Wd   = (const float*)d_in[8];
    const float* bd   = (const float*)d_in[9];
    float* y  = (float*)d_out;

    float* wr = (float*)d_ws;                 // 8192*32
    float* h  = wr + 8192 * 32;               // 8192*64
    float* g  = h  + 8192 * 64;               // 8192*1024   (total ~36.7 MB of ws)

    k_route <<<128,  64, 0, stream>>>(nidx, nw, rec, wr);
    k_stageA<<<1024, 512, 0, stream>>>(x, wr, A1, A2, h);
    k_stageB<<<1024, 512, 0, stream>>>(h, wr, B1, B2, g);
    k_down  <<<256,  256, 0, stream>>>(g, Wd, bd, y);
}

// Round 3
// 188.601 us; speedup vs baseline: 8.3932x; 1.4400x over previous
//
#include <hip/hip_runtime.h>
#include <math.h>

// Problem constants
//   B*S = 8192 tokens, K=8 selected neurons, N_BASIS=32, RANK=8
//   D_MODEL=256 (16x16), hidden 64 (8x8), D_HID=1024 (32x32)
// Workspace layout (floats): wr[8192][32] | h[8192][64] | g[8192][1024]  (~36.7 MB)

__device__ __forceinline__ float gelu_exact(float v) {
    return 0.5f * v * (1.0f + erff(v * 0.70710678118654752440f));
}

// ---------------- K1: routing -> wr[token][32] ----------------
__global__ __launch_bounds__(64) void k_route(
    const int* __restrict__ nidx, const float* __restrict__ nw,
    const float* __restrict__ recipes, float* __restrict__ wr_out)
{
    const int t = blockIdx.x * 64 + threadIdx.x;   // 8192 tokens
    float acc[32];
#pragma unroll
    for (int n = 0; n < 32; n++) acc[n] = 0.f;
#pragma unroll
    for (int k = 0; k < 8; k++) {
        const int   id = nidx[t * 8 + k];
        const float wk = nw[t * 8 + k];
        const float4* row = (const float4*)(recipes + id * 32);
        float v[32];
#pragma unroll
        for (int q = 0; q < 8; q++) {
            float4 f = row[q];
            v[q*4+0] = f.x; v[q*4+1] = f.y; v[q*4+2] = f.z; v[q*4+3] = f.w;
        }
        float m = v[0];
#pragma unroll
        for (int n = 1; n < 32; n++) m = fmaxf(m, v[n]);
        float s = 0.f;
#pragma unroll
        for (int n = 0; n < 32; n++) { float e = expf(v[n] - m); v[n] = e; s += e; }
        const float iv = wk / s;
#pragma unroll
        for (int n = 0; n < 32; n++) acc[n] += v[n] * iv;
    }
    float4* o = (float4*)(wr_out + t * 32);
#pragma unroll
    for (int q = 0; q < 8; q++)
        o[q] = make_float4(acc[q*4+0], acc[q*4+1], acc[q*4+2], acc[q*4+3]);
}

// ---------------- K2: stage A  x[256] -> h[64], 8 tokens/block ----------------
__global__ __launch_bounds__(512) void k_stageA(
    const float* __restrict__ x, const float* __restrict__ wr,
    const float* __restrict__ A1, const float* __restrict__ A2,
    float* __restrict__ h_out)
{
    __shared__ float ca[8 * 1024];      // cores (cA1 then cA2), [t][1024]
    __shared__ float tl[8 * 1088];      // temp  [t][j(16)][68]
    const int tid = threadIdx.x;
    const int t0  = blockIdx.x * 8;

    // ---- build cA1: thread owns e2 = tid*2 for all 8 tokens (wr via uniform/scalar loads)
    {
        const int e2 = tid * 2;
        float2 c[8];
#pragma unroll
        for (int tt = 0; tt < 8; tt++) c[tt] = make_float2(0.f, 0.f);
#pragma unroll 4
        for (int n = 0; n < 32; n++) {
            const float2 a = *(const float2*)(A1 + n * 1024 + e2);
#pragma unroll
            for (int tt = 0; tt < 8; tt++) {
                const float s = wr[(t0 + tt) * 32 + n];   // uniform -> s_load
                c[tt].x += s * a.x; c[tt].y += s * a.y;
            }
        }
#pragma unroll
        for (int tt = 0; tt < 8; tt++) *(float2*)(ca + tt * 1024 + e2) = c[tt];
    }
    __syncthreads();

    // ---- temp build: thread (t = tid>>6, j = (tid&63)>>2, eh = tid&3) ----
    {
        const int t = tid >> 6, g = tid & 63, j = g >> 2, eh = g & 3;
        float xr[16];
#pragma unroll
        for (int i = 0; i < 16; i++) xr[i] = x[(t0 + t) * 256 + i * 16 + j];
        float tr[16];
#pragma unroll
        for (int q = 0; q < 16; q++) tr[q] = 0.f;
#pragma unroll
        for (int i = 0; i < 16; i++) {
            const float xv = xr[i];
#pragma unroll
            for (int q = 0; q < 4; q++) {
                const float4 cv = *(const float4*)(ca + t * 1024 + i * 64 + eh * 16 + q * 4);
                tr[q*4+0] += xv * cv.x; tr[q*4+1] += xv * cv.y;
                tr[q*4+2] += xv * cv.z; tr[q*4+3] += xv * cv.w;
            }
        }
#pragma unroll
        for (int q = 0; q < 4; q++)
            *(float4*)(tl + t * 1088 + j * 68 + eh * 16 + q * 4) =
                make_float4(tr[q*4+0], tr[q*4+1], tr[q*4+2], tr[q*4+3]);
    }
    __syncthreads();

    // ---- build cA2 into ca (overwrite) ----
    {
        const int e2 = tid * 2;
        float2 c[8];
#pragma unroll
        for (int tt = 0; tt < 8; tt++) c[tt] = make_float2(0.f, 0.f);
#pragma unroll 4
        for (int n = 0; n < 32; n++) {
            const float2 a = *(const float2*)(A2 + n * 1024 + e2);
#pragma unroll
            for (int tt = 0; tt < 8; tt++) {
                const float s = wr[(t0 + tt) * 32 + n];
                c[tt].x += s * a.x; c[tt].y += s * a.y;
            }
        }
#pragma unroll
        for (int tt = 0; tt < 8; tt++) *(float2*)(ca + tt * 1024 + e2) = c[tt];
    }
    __syncthreads();

    // ---- h: thread (t, k = (tid&63)>>3, l = tid&7) ----
    {
        const int t = tid >> 6, g = tid & 63, k = g >> 3, l = g & 7;
        float acc = 0.f;
#pragma unroll
        for (int j = 0; j < 16; j++) {
#pragma unroll
            for (int r = 0; r < 8; r++) {
                acc += tl[t * 1088 + j * 68 + r * 8 + k] *
                       ca[t * 1024 + r * 128 + j * 8 + l];
            }
        }
        h_out[(t0 + t) * 64 + g] = acc;
    }
}

// ---------------- K3: stage B  h[64] -> g[1024]=gelu(out), 8 tokens/block ----------------
// r-pair sliced build with coalesced distinct-lane loads:
//  positions: pos = tid&255 -> b=pos>>7 (cb1/cb2), rr=(pos>>6)&1, q=pos&63 (float4)
//  thread builds its float4 for 4 tokens (token group tg = tid>>8), wr via s_load.
// Then per r-pair: t2 = h x cb1 ; o += t2 x cb2.
__global__ __launch_bounds__(512) void k_stageB(
    const float* __restrict__ hin, const float* __restrict__ wr,
    const float* __restrict__ B1, const float* __restrict__ B2,
    float* __restrict__ g_out)
{
    __shared__ float hs [8 * 64];     // [t][64]
    __shared__ float cb1[8 * 520];    // [t][rr*256 + i*32 + k]
    __shared__ float cb2[8 * 520];    // [t][rr*256 + j*32 + l]
    __shared__ float t2 [8 * 520];    // [t][rr*256 + j*32 + k]
    const int tid = threadIdx.x;
    const int t0  = blockIdx.x * 8;

    hs[tid] = hin[t0 * 64 + tid];

    // ---- build mapping ----
    const int tg_v = tid >> 8;                              // 0..1, wave-uniform
    const int tg   = __builtin_amdgcn_readfirstlane(tg_v);  // force SGPR -> s_load of wr
    const int pos  = tid & 255;
    const int b    = pos >> 7;         // 0: B1->cb1, 1: B2->cb2
    const int rr   = (pos >> 6) & 1;   // r within pair
    const int q    = pos & 63;         // float4 index within 256-float slice
    const float* bankp = b ? B2 : B1;
    const int    rstr  = b ? 256 : 32;
    const int    off0  = b ? (q * 4) : ((q >> 3) * 256 + (q & 7) * 4);
    float* ldst = (b ? cb2 : cb1) + rr * 256 + q * 4 + tg * 4 * 520;
    const float* wrp = wr + (t0 + tg * 4) * 32;             // 4 tokens, stride 32

    // ---- consume mappings ----
    const int tw = tid >> 6;                         // wave id = token
    const int g2 = tid & 63, j2 = g2 >> 3, k42 = g2 & 7;          // P2
    const int k0 = (g2 & 7) * 4, l0 = (g2 >> 3) * 4;              // P3

    float o[4][4];
#pragma unroll
    for (int a = 0; a < 4; a++)
#pragma unroll
        for (int li = 0; li < 4; li++) o[a][li] = 0.f;

    for (int rp = 0; rp < 4; rp++) {
        // ---- P1: build cb1/cb2 for r-pair; distinct-lane coalesced loads ----
        {
            const float* p = bankp + off0 + (rp * 2 + rr) * rstr;
            float4 a0 = make_float4(0.f,0.f,0.f,0.f), a1 = a0, a2 = a0, a3 = a0;
#pragma unroll 4
            for (int n = 0; n < 32; n++) {
                const float4 bv = *(const float4*)(p + n * 2048);
                const float s0 = wrp[0 * 32 + n];
                const float s1 = wrp[1 * 32 + n];
                const float s2 = wrp[2 * 32 + n];
                const float s3 = wrp[3 * 32 + n];
                a0.x += s0 * bv.x; a0.y += s0 * bv.y; a0.z += s0 * bv.z; a0.w += s0 * bv.w;
                a1.x += s1 * bv.x; a1.y += s1 * bv.y; a1.z += s1 * bv.z; a1.w += s1 * bv.w;
                a2.x += s2 * bv.x; a2.y += s2 * bv.y; a2.z += s2 * bv.z; a2.w += s2 * bv.w;
                a3.x += s3 * bv.x; a3.y += s3 * bv.y; a3.z += s3 * bv.z; a3.w += s3 * bv.w;
            }
            *(float4*)(ldst + 0 * 520) = a0;
            *(float4*)(ldst + 1 * 520) = a1;
            *(float4*)(ldst + 2 * 520) = a2;
            *(float4*)(ldst + 3 * 520) = a3;
        }
        __syncthreads();

        // ---- P2: t2[t][rr][j][k] = sum_i hs[t][i*8+j] * cb1[t][rr][i][k] ----
        {
#pragma unroll
            for (int r2 = 0; r2 < 2; r2++) {
                float4 acc = make_float4(0.f, 0.f, 0.f, 0.f);
#pragma unroll
                for (int i = 0; i < 8; i++) {
                    const float  hv = hs[tw * 64 + i * 8 + j2];
                    const float4 cv = *(const float4*)(cb1 + tw * 520 + r2 * 256 + i * 32 + k42 * 4);
                    acc.x += hv * cv.x; acc.y += hv * cv.y;
                    acc.z += hv * cv.z; acc.w += hv * cv.w;
                }
                *(float4*)(t2 + tw * 520 + r2 * 256 + j2 * 32 + k42 * 4) = acc;
            }
        }
        __syncthreads();

        // ---- P3: o[a][li] += sum_{rr,j} t2[t][rr][j][k0+a] * cb2[t][rr][j][l0+li] ----
        {
#pragma unroll
            for (int r2 = 0; r2 < 2; r2++) {
#pragma unroll
                for (int j = 0; j < 8; j++) {
                    const float4 tv4 = *(const float4*)(t2  + tw * 520 + r2 * 256 + j * 32 + k0);
                    const float4 cv4 = *(const float4*)(cb2 + tw * 520 + r2 * 256 + j * 32 + l0);
                    const float tv[4] = {tv4.x, tv4.y, tv4.z, tv4.w};
                    const float cv[4] = {cv4.x, cv4.y, cv4.z, cv4.w};
#pragma unroll
                    for (int a = 0; a < 4; a++)
#pragma unroll
                        for (int li = 0; li < 4; li++)
                            o[a][li] += tv[a] * cv[li];
                }
            }
        }
        __syncthreads();   // before next r-pair build overwrites cb1/cb2/t2
    }

    // ---- gelu + store: thread writes rows k0..k0+3, cols l0..l0+3 of its token ----
    const int tok = t0 + tw;
#pragma unroll
    for (int a = 0; a < 4; a++) {
        float4 vg;
        vg.x = gelu_exact(o[a][0]); vg.y = gelu_exact(o[a][1]);
        vg.z = gelu_exact(o[a][2]); vg.w = gelu_exact(o[a][3]);
        *(float4*)(g_out + tok * 1024 + (k0 + a) * 32 + l0) = vg;
    }
}

// ---------------- K4: down-proj  y = g[8192x1024] @ W[1024x256] + b ----------------
// tile M64 x N128, block 256 (thread m4 x n(4+4)), grid 128*2
__global__ __launch_bounds__(256) void k_down(
    const float* __restrict__ g, const float* __restrict__ W,
    const float* __restrict__ bias, float* __restrict__ y)
{
    __shared__ float gl[64 * 21];    // [m][kk16] pad 21
    __shared__ float wl[16 * 132];   // [kk][n128] pad 132
    const int tid = threadIdx.x;
    const int m0 = (blockIdx.x >> 1) * 64;
    const int n0 = (blockIdx.x & 1) * 128;
    const int mi = tid >> 4, ni = tid & 15;

    float acc[4][8];
#pragma unroll
    for (int a = 0; a < 4; a++)
#pragma unroll
        for (int q = 0; q < 8; q++) acc[a][q] = 0.f;

    for (int kc = 0; kc < 1024; kc += 16) {
        __syncthreads();
        {   // stage g tile: thread stores 4 scalars (pad-21 rows)
            const int idx = tid * 4, m = idx >> 4, kk = idx & 15;
            const float4 v = *(const float4*)(g + (m0 + m) * 1024 + kc + kk);
            gl[m * 21 + kk + 0] = v.x; gl[m * 21 + kk + 1] = v.y;
            gl[m * 21 + kk + 2] = v.z; gl[m * 21 + kk + 3] = v.w;
        }
        {   // stage W tile: thread stores 8 floats
            const int idx = tid * 8, row = idx >> 7, col = idx & 127;
            const float4 v0 = *(const float4*)(W + (kc + row) * 256 + n0 + col);
            const float4 v1 = *(const float4*)(W + (kc + row) * 256 + n0 + col + 4);
            *(float4*)(wl + row * 132 + col)     = v0;
            *(float4*)(wl + row * 132 + col + 4) = v1;
        }
        __syncthreads();
#pragma unroll
        for (int kk = 0; kk < 16; kk++) {
            float gv[4];
#pragma unroll
            for (int a = 0; a < 4; a++) gv[a] = gl[(mi * 4 + a) * 21 + kk];
            const float4 w0 = *(const float4*)(wl + kk * 132 + ni * 4);
            const float4 w1 = *(const float4*)(wl + kk * 132 + 64 + ni * 4);
#pragma unroll
            for (int a = 0; a < 4; a++) {
                acc[a][0] += gv[a] * w0.x; acc[a][1] += gv[a] * w0.y;
                acc[a][2] += gv[a] * w0.z; acc[a][3] += gv[a] * w0.w;
                acc[a][4] += gv[a] * w1.x; acc[a][5] += gv[a] * w1.y;
                acc[a][6] += gv[a] * w1.z; acc[a][7] += gv[a] * w1.w;
            }
        }
    }
    const float4 b0 = *(const float4*)(bias + n0 + ni * 4);
    const float4 b1 = *(const float4*)(bias + n0 + 64 + ni * 4);
#pragma unroll
    for (int a = 0; a < 4; a++) {
        const int row = m0 + mi * 4 + a;
        float4 o0 = make_float4(acc[a][0] + b0.x, acc[a][1] + b0.y,
                                acc[a][2] + b0.z, acc[a][3] + b0.w);
        float4 o1 = make_float4(acc[a][4] + b1.x, acc[a][5] + b1.y,
                                acc[a][6] + b1.z, acc[a][7] + b1.w);
        *(float4*)(y + row * 256 + n0 + ni * 4)      = o0;
        *(float4*)(y + row * 256 + n0 + 64 + ni * 4) = o1;
    }
}

extern "C" void kernel_launch(void* const* d_in, const int* in_sizes, int n_in,
                              void* d_out, int out_size, void* d_ws, size_t ws_size,
                              hipStream_t stream)
{
    const float* x    = (const float*)d_in[0];
    const int*   nidx = (const int*)  d_in[1];
    const float* nw   = (const float*)d_in[2];
    const float* rec  = (const float*)d_in[3];
    const float* A1   = (const float*)d_in[4];
    const float* A2   = (const float*)d_in[5];
    const float* B1   = (const float*)d_in[6];
    const float* B2   = (const float*)d_in[7];
    const float* Wd   = (const float*)d_in[8];
    const float* bd   = (const float*)d_in[9];
    float* y  = (float*)d_out;

    float* wr = (float*)d_ws;                 // 8192*32
    float* h  = wr + 8192 * 32;               // 8192*64
    float* g  = h  + 8192 * 64;               // 8192*1024   (total ~36.7 MB of ws)

    k_route <<<128,  64, 0, stream>>>(nidx, nw, rec, wr);
    k_stageA<<<1024, 512, 0, stream>>>(x, wr, A1, A2, h);
    k_stageB<<<1024, 512, 0, stream>>>(h, wr, B1, B2, g);
    k_down  <<<256,  256, 0, stream>>>(g, Wd, bd, y);
}